// Round 9
// baseline (311.890 us; speedup 1.0000x reference)
//
#include <hip/hip_runtime.h>

// Problem constants
#define N 65536     // B*H*W rows
#define D 256
#define K 1024
#define BETA 0.25f
#define GAMMA 0.9f
#define EPS 1e-5f

#define DWROWS 64    // perm rows per dw_fused block

// Workspace layout (bytes)
#define OFF_INDICES 0                 // N int
#define OFF_PERM    262144            // N int (packed n | k<<16)
#define OFF_COUNTS  524288            // (unused)
#define OFF_CNORM   528384            // K float; reused as lossp (1024 f) after argmin
#define OFF_OFFSETS 532480            // (unused)
#define OFF_CURSOR  536576            // (unused; cursor lives in finalize LDS now)
#define OFF_SMOOTH  540672            // K float
#define OFF_LOSSP   544768            // (unused)
#define OFF_CBT     546816            // K*D float (1 MB); live until dw_fused
#define OFF_CBE     1595392           // packed B 1 MB; reused as dwT (K*D float) after argmin

typedef __bf16 bf16x8 __attribute__((ext_vector_type(8)));
typedef short  s16x8  __attribute__((ext_vector_type(8)));
typedef float  f32x4  __attribute__((ext_vector_type(4)));

__device__ inline unsigned short f32_to_bf16_rn(float f) {
    unsigned int u = __float_as_uint(f);
    unsigned int r = u + 0x7fffu + ((u >> 16) & 1u);
    return (unsigned short)(r >> 16);
}

__device__ inline f32x4 mfma16(s16x8 a, s16x8 b, f32x4 c) {
    return __builtin_amdgcn_mfma_f32_16x16x32_bf16(
        __builtin_bit_cast(bf16x8, a), __builtin_bit_cast(bf16x8, b), c, 0, 0, 0);
}

// global->LDS direct DMA, 16B/lane. LDS dest = wave-uniform base + lane*16.
__device__ __forceinline__ void stage16(const s16x8* __restrict__ g, s16x8* l) {
    __builtin_amdgcn_global_load_lds(
        (const __attribute__((address_space(1))) void*)g,
        (__attribute__((address_space(3))) void*)l, 16, 0, 0);
}

// ---------------------------------------------------------------------------
// pack_cb v3: cb [D][K] -> cbT [K][D] fp32 + cbEp packed bf16 units + cnorm.
// R9: one 4-lane shfl group (lanes L, L+16, L+32, L+48) covers a FULL column
// norm -> cnorm is plain-stored (no atomics, NO memset dispatch needed).
// Grid 16 blocks (ct); wave w = frgc; thread covers all (c2 in 4, ks in 2)
// units for its (frgc, L): 8 units x 8 dims = 64 dims of column c; the 4
// lanes of the shfl group cover disjoint (L>>4) slots -> 256 dims total.
// cbEp/cbT/cnorm addresses byte-identical to the R7/R8 layout:
//   u = frgc*128 + ks*64 + L; chunk (ct*8 + c2) hi, (ct*8+4+c2) lo.
__global__ __launch_bounds__(256) void pack_cb(const float* __restrict__ cb,
                                               float* __restrict__ cbT,
                                               s16x8* __restrict__ cbEp,
                                               float* __restrict__ cnorm) {
    const int ct = blockIdx.x;          // 0..15
    const int w  = threadIdx.x >> 6;    // frgc 0..3
    const int L  = threadIdx.x & 63;
    const int c  = ct * 64 + w * 16 + (L & 15);
    float ss = 0.f;
#pragma unroll
    for (int c2 = 0; c2 < 4; ++c2) {
#pragma unroll
        for (int ks = 0; ks < 2; ++ks) {
            const int d0 = c2 * 64 + (ks * 4 + (L >> 4)) * 8;
            const int u  = w * 128 + ks * 64 + L;
            float v[8];
            s16x8 hv, lv;
#pragma unroll
            for (int j = 0; j < 8; ++j) {
                float f = cb[(size_t)(d0 + j) * K + c];
                v[j] = f;
                unsigned short h = f32_to_bf16_rn(f);
                hv[j] = (short)h;
                lv[j] = (short)f32_to_bf16_rn(f - __uint_as_float((unsigned)h << 16));
                ss = fmaf(f, f, ss);
            }
            *(float4*)&cbT[(size_t)c * D + d0]     = make_float4(v[0], v[1], v[2], v[3]);
            *(float4*)&cbT[(size_t)c * D + d0 + 4] = make_float4(v[4], v[5], v[6], v[7]);
            cbEp[(size_t)(ct * 8 + c2) * 512 + u]     = hv;   // hi chunk
            cbEp[(size_t)(ct * 8 + 4 + c2) * 512 + u] = lv;   // lo chunk
        }
    }
    // full-column norm across the 4-lane group (stride 16), plain store
    ss += __shfl_xor(ss, 16, 64);
    ss += __shfl_xor(ss, 32, 64);
    if ((L >> 4) == 0) cnorm[c] = ss;
}

// ---------------------------------------------------------------------------
// Register-A MFMA argmin — FROZEN (R3 source; 110-126 us, session-dependent).
// R6 lesson: ANY change to live ranges (even 8 trailing atomics) perturbs
// regalloc, moves spill into the hot loop, costs ~30 us. Guard counters:
// VGPR_Count=128, WRITE_SIZE=23808 KB, MfmaUtil ~34-39%.
// Layouts (verified R3): A lane L = A[m=L&15][k=(L>>4)*8+j];
// B lane L = B[k=(L>>4)*8+j][n=L&15]; D: col=L&15, row=(L>>4)*4+reg.
__global__ __launch_bounds__(256, 2) void argmin_mfma_kernel(
        const float* __restrict__ x,
        const s16x8* __restrict__ cbEp,
        const float* __restrict__ cnorm,
        int* __restrict__ indices) {
    __shared__ s16x8 Bs[2][1024];   // 32 KB double buffer (2 chunks per half)

    const int tid = threadIdx.x;       // 0..255
    const int lane = tid & 63;
    const int w = tid >> 6;            // wave id 0..3 (32 rows each)
    const int r0 = blockIdx.x * 128;
    const int row16 = lane & 15;
    const int quad = lane >> 4;

    // ---- prologue: stage chunk pair (ct=0, c=0,1) into buf0 (flies over A-conv)
#pragma unroll
    for (int i = 0; i < 4; ++i)
        stage16(cbEp + i * 256 + tid, &Bs[0][i * 256 + w * 64]);

    // ---- phase 1: load + convert this wave's 32 rows into A fragments ----
    s16x8 Ah[2][8], Al[2][8];
#pragma unroll
    for (int frg = 0; frg < 2; ++frg) {
#pragma unroll
        for (int kb8 = 0; kb8 < 8; ++kb8) {
            const float* src = &x[(size_t)(r0 + w * 32 + frg * 16 + row16) * D
                                  + kb8 * 32 + quad * 8];
            float4 v0 = *(const float4*)src;
            float4 v1 = *(const float4*)(src + 4);
            float f[8] = {v0.x, v0.y, v0.z, v0.w, v1.x, v1.y, v1.z, v1.w};
            s16x8 hv, lv;
#pragma unroll
            for (int j = 0; j < 8; ++j) {
                unsigned short h = f32_to_bf16_rn(f[j]);
                hv[j] = (short)h;
                lv[j] = (short)f32_to_bf16_rn(f[j] - __uint_as_float((unsigned)h << 16));
            }
            Ah[frg][kb8] = hv;
            Al[frg][kb8] = lv;
        }
    }

    float minv[2][4];
    int   mini[2][4];
#pragma unroll
    for (int frg = 0; frg < 2; ++frg)
#pragma unroll
        for (int reg = 0; reg < 4; ++reg) { minv[frg][reg] = 3.4e38f; mini[frg][reg] = 0; }

    for (int ct = 0; ct < 16; ++ct) {
        f32x4 acc[2][4];
#pragma unroll
        for (int frg = 0; frg < 2; ++frg)
#pragma unroll
            for (int fc = 0; fc < 4; ++fc) acc[frg][fc] = (f32x4){0.f, 0.f, 0.f, 0.f};

#pragma unroll
        for (int ph = 0; ph < 4; ++ph) {   // chunk pair (2ph, 2ph+1); buf = ph&1
            __syncthreads();   // buf(ph&1) staged & visible; buf^1 readers done
            const bool has_next = !(ct == 15 && ph == 3);
            if (has_next) {
                const int nct = (ph == 3) ? ct + 1 : ct;
                const int nph = (ph == 3) ? 0 : ph + 1;
                const size_t gb = (size_t)(nct * 8 + nph * 2) * 512;  // pair contiguous
#pragma unroll
                for (int i = 0; i < 4; ++i)
                    stage16(cbEp + gb + i * 256 + tid, &Bs[(ph + 1) & 1][i * 256 + w * 64]);
            }
#pragma unroll
            for (int half = 0; half < 2; ++half) {
                const int cchunk = ph * 2 + half;        // 0..7 (0-3 eh, 4-7 el)
                const int c2 = cchunk & 3;               // d-quarter
#pragma unroll
                for (int ks = 0; ks < 2; ++ks) {
                    const int ksb = c2 * 2 + ks;         // A k-octet index
#pragma unroll
                    for (int fc = 0; fc < 4; ++fc) {
                        s16x8 b = Bs[ph & 1][half * 512 + (fc * 2 + ks) * 64 + lane];
#pragma unroll
                        for (int frg = 0; frg < 2; ++frg) {
                            acc[frg][fc] = mfma16(Ah[frg][ksb], b, acc[frg][fc]);
                            if (cchunk < 4)              // eh chunk also feeds lo term
                                acc[frg][fc] = mfma16(Al[frg][ksb], b, acc[frg][fc]);
                        }
                    }
                }
            }
        }
        // ---- argmin epilogue for this 64-col tile (ascending col, strict <) ----
#pragma unroll
        for (int fc = 0; fc < 4; ++fc) {
            int col = ct * 64 + fc * 16 + row16;
            float cn = cnorm[col];
#pragma unroll
            for (int frg = 0; frg < 2; ++frg)
#pragma unroll
                for (int reg = 0; reg < 4; ++reg) {
                    float val = fmaf(-2.f, acc[frg][fc][reg], cn);
                    if (val < minv[frg][reg]) { minv[frg][reg] = val; mini[frg][reg] = col; }
                }
        }
    }

    // butterfly over the 16-lane col group; tie -> lower index
#pragma unroll
    for (int mask = 1; mask <= 8; mask <<= 1) {
#pragma unroll
        for (int frg = 0; frg < 2; ++frg)
#pragma unroll
            for (int reg = 0; reg < 4; ++reg) {
                float ov = __shfl_xor(minv[frg][reg], mask, 64);
                int   oi = __shfl_xor(mini[frg][reg], mask, 64);
                if (ov < minv[frg][reg] ||
                    (ov == minv[frg][reg] && oi < mini[frg][reg])) {
                    minv[frg][reg] = ov; mini[frg][reg] = oi;
                }
            }
    }
    // rows are wave-private: direct write, no cross-wave reduction needed
    if (row16 == 0) {
#pragma unroll
        for (int frg = 0; frg < 2; ++frg)
#pragma unroll
            for (int reg = 0; reg < 4; ++reg)
                indices[r0 + w * 32 + frg * 16 + quad * 4 + reg] = mini[frg][reg];
    }
}

// ---------------------------------------------------------------------------
// R9 merged single-block kernel: dwT zero + histogram + EMA stats +
// perplexity + prefix-scan + SCATTER (permk build via LDS cursor atomics)
// + smoothed. Replaces finalize + scatter + dwT-memset (3 dispatches -> 1).
// indices cached in 16 int4 regs (fully unrolled -> stays in VGPRs).
// Within-cluster perm order is arbitrary — dw is an unordered sum.
__global__ __launch_bounds__(1024) void finalize_scatter_kernel(
        const int* __restrict__ indices,
        const float* __restrict__ ema_c,
        const int* __restrict__ counter,
        float* __restrict__ out_perp,
        float* __restrict__ smoothed,
        int* __restrict__ permk,
        float* __restrict__ dwT) {
    const int k = threadIdx.x;
    const int lane = k & 63;
    const int wave = k >> 6;
    __shared__ int hist[1024];
    __shared__ int curs[1024];
    __shared__ float wsum[16], went[16];
    __shared__ int wtot[16];

    hist[k] = 0;
    // zero dwT (1 MB): independent stores, fly under the index loads
    float4* dwT4 = (float4*)dwT;
    const float4 z = make_float4(0.f, 0.f, 0.f, 0.f);
#pragma unroll 8
    for (int i = 0; i < 64; ++i) dwT4[(size_t)i * 1024 + k] = z;
    __syncthreads();

    // load + histogram (65536 indices = 16 int4 per thread, coalesced)
    const int4* idx4 = (const int4*)indices;
    int4 v[16];
#pragma unroll
    for (int i = 0; i < 16; ++i) {
        v[i] = idx4[(size_t)i * 1024 + k];
        atomicAdd(&hist[v[i].x], 1);
        atomicAdd(&hist[v[i].y], 1);
        atomicAdd(&hist[v[i].z], 1);
        atomicAdd(&hist[v[i].w], 1);
    }
    __syncthreads();

    const int c = hist[k];
    const float bias = 1.0f - powf(GAMMA, (float)counter[0]);
    const float avg = fmaf(ema_c[k], GAMMA, (float)c * (1.0f - GAMMA)) / bias;
    const float p = (float)c * (1.0f / (float)N);
    const float ent = p * logf(p + 1e-10f);

    // wave-level reductions (nsum, entropy) + inclusive scan of c
    float a = avg, e = ent;
#pragma unroll
    for (int off = 32; off >= 1; off >>= 1) {
        a += __shfl_down(a, off, 64);
        e += __shfl_down(e, off, 64);
    }
    int sv = c;
#pragma unroll
    for (int off = 1; off < 64; off <<= 1) {
        int t = __shfl_up(sv, off, 64);
        if (lane >= off) sv += t;
    }
    if (lane == 0)  { wsum[wave] = a; went[wave] = e; }
    if (lane == 63) { wtot[wave] = sv; }
    __syncthreads();

    float nsum = 0.f, entt = 0.f;
    int woff = 0;
#pragma unroll
    for (int i = 0; i < 16; ++i) {
        nsum += wsum[i];
        entt += went[i];
        if (i < wave) woff += wtot[i];
    }
    curs[k] = woff + sv - c;                  // exclusive prefix over counts
    smoothed[k] = (avg + EPS) / (nsum + (float)K * EPS) * nsum;
    if (k == 0) out_perp[0] = expf(-entt);
    __syncthreads();

    // scatter: build packed perm (n | k<<16) via LDS cursor atomics
#pragma unroll
    for (int i = 0; i < 16; ++i) {
        const int n0 = (i * 1024 + k) * 4;
        int pos;
        pos = atomicAdd(&curs[v[i].x], 1); permk[pos] = (n0 + 0) | (v[i].x << 16);
        pos = atomicAdd(&curs[v[i].y], 1); permk[pos] = (n0 + 1) | (v[i].y << 16);
        pos = atomicAdd(&curs[v[i].z], 1); permk[pos] = (n0 + 2) | (v[i].z << 16);
        pos = atomicAdd(&curs[v[i].w], 1); permk[pos] = (n0 + 3) | (v[i].w << 16);
    }
}

// ---------------------------------------------------------------------------
// Fused tail pass over cluster-sorted rows: segmented dw reduction + ste
// write + loss partials. float4 lanes; block = 4 wave-groups, each owns
// 16 contiguous perm rows; lane d4 covers dims [4*d4, 4*d4+4). Flush branch
// is wave-uniform; forced flush at segment end keeps groups independent.
__global__ __launch_bounds__(256) void dw_fused_kernel(const float* __restrict__ x,
                                                       const float* __restrict__ cbT,
                                                       const int* __restrict__ permk,
                                                       float* __restrict__ ste,
                                                       float* __restrict__ dwT,
                                                       float* __restrict__ lossp) {
    __shared__ int s_rows[DWROWS];
    __shared__ int s_keys[DWROWS];
    const int tid = threadIdx.x;
    const int g = tid >> 6;        // row sub-segment 0..3 (16 rows each)
    const int d4 = tid & 63;       // float4 slot
    const int base = blockIdx.x * DWROWS;
    if (tid < DWROWS) {
        const int pk = permk[base + tid];
        s_rows[tid] = pk & 0xffff;
        s_keys[tid] = pk >> 16;
    }
    __syncthreads();

    const float4* x4   = (const float4*)x;    // row stride 64
    const float4* cbT4 = (const float4*)cbT;
    float4*       ste4 = (float4*)ste;

    float ax = 0.f, ay = 0.f, az = 0.f, aw = 0.f;
    float ls = 0.f;
    const int r0 = g * 16;
#pragma unroll
    for (int i = 0; i < 16; ++i) {
        const int r = r0 + i;
        const int n = s_rows[r];
        const int k = s_keys[r];
        const float4 xv = x4[(size_t)n * 64 + d4];
        const float4 q  = cbT4[(size_t)k * 64 + d4];   // L2-resident
        ste4[(size_t)n * 64 + d4] = q;
        ax += xv.x; ay += xv.y; az += xv.z; aw += xv.w;
        float dx = q.x - xv.x, dy = q.y - xv.y, dz = q.z - xv.z, dw = q.w - xv.w;
        ls = fmaf(dx, dx, ls); ls = fmaf(dy, dy, ls);
        ls = fmaf(dz, dz, ls); ls = fmaf(dw, dw, ls);
        const int nk = (i == 15) ? -1 : s_keys[r + 1];
        if (nk != k) {                                  // wave-uniform branch
            float* dst = &dwT[(size_t)k * D + d4 * 4];
            atomicAdd(dst + 0, ax);
            atomicAdd(dst + 1, ay);
            atomicAdd(dst + 2, az);
            atomicAdd(dst + 3, aw);
            ax = ay = az = aw = 0.f;
        }
    }
    // loss partial: wave shuffle + cross-wave LDS reduce
#pragma unroll
    for (int off = 32; off >= 1; off >>= 1) ls += __shfl_down(ls, off, 64);
    __shared__ float red[4];
    if ((tid & 63) == 0) red[tid >> 6] = ls;
    __syncthreads();
    if (tid == 0) lossp[blockIdx.x] = red[0] + red[1] + red[2] + red[3];
}

// ---------------------------------------------------------------------------
// out_cb[d][k] = ((ema_dw[d][k]*g + dwT[k][d]*(1-g))/bias)/smoothed[k]
// LDS 64x64 transpose so both global reads and writes are coalesced.
// Block 0 additionally reduces the 1024 loss partials -> out_loss.
__global__ __launch_bounds__(256) void codebook_final_kernel(const float* __restrict__ dwT,
                                                             const float* __restrict__ ema_dw,
                                                             const float* __restrict__ smoothed,
                                                             const int* __restrict__ counter,
                                                             const float* __restrict__ lossp,
                                                             float* __restrict__ out_cb,
                                                             float* __restrict__ out_loss) {
    __shared__ float tile[64][65];
    __shared__ float lred[4];
    const int tid = threadIdx.x;

    if (blockIdx.x == 0) {
        float s = lossp[tid] + lossp[tid + 256] + lossp[tid + 512] + lossp[tid + 768];
#pragma unroll
        for (int off = 32; off >= 1; off >>= 1) s += __shfl_down(s, off, 64);
        if ((tid & 63) == 0) lred[tid >> 6] = s;
        __syncthreads();
        if (tid == 0)
            out_loss[0] = BETA * (lred[0] + lred[1] + lred[2] + lred[3])
                          * (1.0f / ((float)N * (float)D));
        __syncthreads();
    }

    const int d0 = (blockIdx.x & 3) * 64;
    const int k0 = (blockIdx.x >> 2) * 64;
#pragma unroll
    for (int it = 0; it < 16; ++it) {
        int idx = it * 256 + tid;
        int kk = idx >> 6, dd = idx & 63;
        tile[kk][dd] = dwT[(size_t)(k0 + kk) * D + d0 + dd];   // coalesced in d
    }
    __syncthreads();
    const float bias = 1.0f - powf(GAMMA, (float)counter[0]);
#pragma unroll
    for (int it = 0; it < 16; ++it) {
        int idx = it * 256 + tid;
        int dd = idx >> 6, kk = idx & 63;
        float dwv = tile[kk][dd];                               // 2-way LDS alias: free
        float hid = fmaf(ema_dw[(size_t)(d0 + dd) * K + k0 + kk], GAMMA,
                         dwv * (1.0f - GAMMA));
        out_cb[(size_t)(d0 + dd) * K + k0 + kk] = (hid / bias) / smoothed[k0 + kk];
    }
}

// ---------------------------------------------------------------------------
extern "C" void kernel_launch(void* const* d_in, const int* in_sizes, int n_in,
                              void* d_out, int out_size, void* d_ws, size_t ws_size,
                              hipStream_t stream) {
    const float* x       = (const float*)d_in[0];  // [N, D]
    const float* cb      = (const float*)d_in[1];  // [D, K]
    const float* ema_c   = (const float*)d_in[2];  // [K]
    const float* ema_dw  = (const float*)d_in[3];  // [D, K]
    const int*   counter = (const int*)d_in[4];

    float* out = (float*)d_out;
    float* ste = out;                        // N*D
    float* out_perp = out + (size_t)N * D;   // 1
    float* out_loss = out_perp + 1;          // 1
    float* out_cb = out_perp + 2;            // D*K

    char* ws = (char*)d_ws;
    int* indices  = (int*)(ws + OFF_INDICES);
    int* permk    = (int*)(ws + OFF_PERM);
    float* cnorm  = (float*)(ws + OFF_CNORM);
    float* smooth = (float*)(ws + OFF_SMOOTH);
    float* cbT    = (float*)(ws + OFF_CBT);
    s16x8* cbEp   = (s16x8*)(ws + OFF_CBE);
    float* dwT    = (float*)(ws + OFF_CBE);   // reuse: cbEp dead after argmin
    float* lossp  = (float*)(ws + OFF_CNORM); // reuse: cnorm dead after argmin

    // 5 dispatches, zero memsets (cnorm plain-stored; dwT zeroed in finalize)
    pack_cb<<<16, 256, 0, stream>>>(cb, cbT, cbEp, cnorm);
    argmin_mfma_kernel<<<N / 128, 256, 0, stream>>>(x, cbEp, cnorm, indices);
    finalize_scatter_kernel<<<1, 1024, 0, stream>>>(indices, ema_c, counter,
                                                    out_perp, smooth, permk, dwT);
    dw_fused_kernel<<<N / DWROWS, 256, 0, stream>>>(x, cbT, permk, ste, dwT, lossp);
    codebook_final_kernel<<<64, 256, 0, stream>>>(dwT, ema_dw, smooth, counter,
                                                  lossp, out_cb, out_loss);
}

// Round 10
// 285.818 us; speedup vs baseline: 1.0912x; 1.0912x over previous
//
#include <hip/hip_runtime.h>

// Problem constants
#define N 65536     // B*H*W rows
#define D 256
#define K 1024
#define BETA 0.25f
#define GAMMA 0.9f
#define EPS 1e-5f

#define DWROWS 64    // perm rows per dw_fused block

// Workspace layout (bytes)
#define OFF_INDICES 0                 // N int
#define OFF_PERM    262144            // N int (packed n | k<<16)
#define OFF_COUNTS  524288            // (unused; histogram lives in finalize LDS)
#define OFF_CNORM   528384            // K float; reused as lossp (1024 f) after argmin
#define OFF_OFFSETS 532480            // (unused, kept for layout stability)
#define OFF_CURSOR  536576            // K int
#define OFF_SMOOTH  540672            // K float
#define OFF_LOSSP   544768            // (unused)
#define OFF_CBT     546816            // K*D float (1 MB); live until dw_fused
#define OFF_CBE     1595392           // packed B 1 MB; reused as dwT (K*D float) after argmin

typedef __bf16 bf16x8 __attribute__((ext_vector_type(8)));
typedef short  s16x8  __attribute__((ext_vector_type(8)));
typedef float  f32x4  __attribute__((ext_vector_type(4)));

__device__ inline unsigned short f32_to_bf16_rn(float f) {
    unsigned int u = __float_as_uint(f);
    unsigned int r = u + 0x7fffu + ((u >> 16) & 1u);
    return (unsigned short)(r >> 16);
}

__device__ inline f32x4 mfma16(s16x8 a, s16x8 b, f32x4 c) {
    return __builtin_amdgcn_mfma_f32_16x16x32_bf16(
        __builtin_bit_cast(bf16x8, a), __builtin_bit_cast(bf16x8, b), c, 0, 0, 0);
}

// global->LDS direct DMA, 16B/lane. LDS dest = wave-uniform base + lane*16.
__device__ __forceinline__ void stage16(const s16x8* __restrict__ g, s16x8* l) {
    __builtin_amdgcn_global_load_lds(
        (const __attribute__((address_space(1))) void*)g,
        (__attribute__((address_space(3))) void*)l, 16, 0, 0);
}

// ---------------------------------------------------------------------------
// pack_cb: cb [D][K] -> cbT [K][D] fp32 (exact entries for ste)
//        + cbEp packed bf16 B-fragment units + cnorm (atomic partials).
// Unit order for a 64col x 64k tile: u = (frgc*2+ks)*64 + (o&3)*16 + (c&15);
// physical chunks per ct: 0-3 = eh (hi) d-quarters, 4-7 = el (lo) d-quarters.
// NOTE (R9 post-mortem): this is the configuration from the best-measured
// run (287 us). R8/R9 tail restructures (pack grid changes, shuffle
// finalize, float4 dw_fused, 5-dispatch merge) all measured neutral or
// worse; reverted wholesale.
__global__ __launch_bounds__(256) void pack_cb(const float* __restrict__ cb,
                                               float* __restrict__ cbT,
                                               s16x8* __restrict__ cbEp,
                                               float* __restrict__ cnorm) {
    const int ct = blockIdx.x >> 2;
    const int c2 = blockIdx.x & 3;
#pragma unroll
    for (int it = 0; it < 2; ++it) {
        int u = it * 256 + threadIdx.x;
        int frgc = u >> 7;
        int ks = (u >> 6) & 1;
        int L = u & 63;
        int c = ct * 64 + frgc * 16 + (L & 15);
        int d0 = c2 * 64 + (ks * 4 + (L >> 4)) * 8;
        float v[8];
        s16x8 hv, lv;
        float ss = 0.f;
#pragma unroll
        for (int j = 0; j < 8; ++j) {
            float f = cb[(size_t)(d0 + j) * K + c];
            v[j] = f;
            unsigned short h = f32_to_bf16_rn(f);
            hv[j] = (short)h;
            lv[j] = (short)f32_to_bf16_rn(f - __uint_as_float((unsigned)h << 16));
            ss = fmaf(f, f, ss);
        }
        *(float4*)&cbT[(size_t)c * D + d0]     = make_float4(v[0], v[1], v[2], v[3]);
        *(float4*)&cbT[(size_t)c * D + d0 + 4] = make_float4(v[4], v[5], v[6], v[7]);
        cbEp[(size_t)(ct * 8 + c2) * 512 + u]     = hv;   // hi chunk
        cbEp[(size_t)(ct * 8 + 4 + c2) * 512 + u] = lv;   // lo chunk
        atomicAdd(&cnorm[c], ss);                          // 32 adds/col total
    }
}

// ---------------------------------------------------------------------------
// Register-A MFMA argmin — FROZEN (R3 source; 110-126 us, session-dependent).
// R6 lesson: ANY change to live ranges (even 8 trailing atomics) perturbs
// regalloc, moves spill into the hot loop, costs ~30 us. Guard counters:
// VGPR_Count=128, WRITE_SIZE=23808 KB, MfmaUtil ~34-39%, LDS=32768.
// Layouts (verified R3): A lane L = A[m=L&15][k=(L>>4)*8+j];
// B lane L = B[k=(L>>4)*8+j][n=L&15]; D: col=L&15, row=(L>>4)*4+reg.
__global__ __launch_bounds__(256, 2) void argmin_mfma_kernel(
        const float* __restrict__ x,
        const s16x8* __restrict__ cbEp,
        const float* __restrict__ cnorm,
        int* __restrict__ indices) {
    __shared__ s16x8 Bs[2][1024];   // 32 KB double buffer (2 chunks per half)

    const int tid = threadIdx.x;       // 0..255
    const int lane = tid & 63;
    const int w = tid >> 6;            // wave id 0..3 (32 rows each)
    const int r0 = blockIdx.x * 128;
    const int row16 = lane & 15;
    const int quad = lane >> 4;

    // ---- prologue: stage chunk pair (ct=0, c=0,1) into buf0 (flies over A-conv)
#pragma unroll
    for (int i = 0; i < 4; ++i)
        stage16(cbEp + i * 256 + tid, &Bs[0][i * 256 + w * 64]);

    // ---- phase 1: load + convert this wave's 32 rows into A fragments ----
    s16x8 Ah[2][8], Al[2][8];
#pragma unroll
    for (int frg = 0; frg < 2; ++frg) {
#pragma unroll
        for (int kb8 = 0; kb8 < 8; ++kb8) {
            const float* src = &x[(size_t)(r0 + w * 32 + frg * 16 + row16) * D
                                  + kb8 * 32 + quad * 8];
            float4 v0 = *(const float4*)src;
            float4 v1 = *(const float4*)(src + 4);
            float f[8] = {v0.x, v0.y, v0.z, v0.w, v1.x, v1.y, v1.z, v1.w};
            s16x8 hv, lv;
#pragma unroll
            for (int j = 0; j < 8; ++j) {
                unsigned short h = f32_to_bf16_rn(f[j]);
                hv[j] = (short)h;
                lv[j] = (short)f32_to_bf16_rn(f[j] - __uint_as_float((unsigned)h << 16));
            }
            Ah[frg][kb8] = hv;
            Al[frg][kb8] = lv;
        }
    }

    float minv[2][4];
    int   mini[2][4];
#pragma unroll
    for (int frg = 0; frg < 2; ++frg)
#pragma unroll
        for (int reg = 0; reg < 4; ++reg) { minv[frg][reg] = 3.4e38f; mini[frg][reg] = 0; }

    for (int ct = 0; ct < 16; ++ct) {
        f32x4 acc[2][4];
#pragma unroll
        for (int frg = 0; frg < 2; ++frg)
#pragma unroll
            for (int fc = 0; fc < 4; ++fc) acc[frg][fc] = (f32x4){0.f, 0.f, 0.f, 0.f};

#pragma unroll
        for (int ph = 0; ph < 4; ++ph) {   // chunk pair (2ph, 2ph+1); buf = ph&1
            __syncthreads();   // buf(ph&1) staged & visible; buf^1 readers done
            const bool has_next = !(ct == 15 && ph == 3);
            if (has_next) {
                const int nct = (ph == 3) ? ct + 1 : ct;
                const int nph = (ph == 3) ? 0 : ph + 1;
                const size_t gb = (size_t)(nct * 8 + nph * 2) * 512;  // pair contiguous
#pragma unroll
                for (int i = 0; i < 4; ++i)
                    stage16(cbEp + gb + i * 256 + tid, &Bs[(ph + 1) & 1][i * 256 + w * 64]);
            }
#pragma unroll
            for (int half = 0; half < 2; ++half) {
                const int cchunk = ph * 2 + half;        // 0..7 (0-3 eh, 4-7 el)
                const int c2 = cchunk & 3;               // d-quarter
#pragma unroll
                for (int ks = 0; ks < 2; ++ks) {
                    const int ksb = c2 * 2 + ks;         // A k-octet index
#pragma unroll
                    for (int fc = 0; fc < 4; ++fc) {
                        s16x8 b = Bs[ph & 1][half * 512 + (fc * 2 + ks) * 64 + lane];
#pragma unroll
                        for (int frg = 0; frg < 2; ++frg) {
                            acc[frg][fc] = mfma16(Ah[frg][ksb], b, acc[frg][fc]);
                            if (cchunk < 4)              // eh chunk also feeds lo term
                                acc[frg][fc] = mfma16(Al[frg][ksb], b, acc[frg][fc]);
                        }
                    }
                }
            }
        }
        // ---- argmin epilogue for this 64-col tile (ascending col, strict <) ----
#pragma unroll
        for (int fc = 0; fc < 4; ++fc) {
            int col = ct * 64 + fc * 16 + row16;
            float cn = cnorm[col];
#pragma unroll
            for (int frg = 0; frg < 2; ++frg)
#pragma unroll
                for (int reg = 0; reg < 4; ++reg) {
                    float val = fmaf(-2.f, acc[frg][fc][reg], cn);
                    if (val < minv[frg][reg]) { minv[frg][reg] = val; mini[frg][reg] = col; }
                }
        }
    }

    // butterfly over the 16-lane col group; tie -> lower index
#pragma unroll
    for (int mask = 1; mask <= 8; mask <<= 1) {
#pragma unroll
        for (int frg = 0; frg < 2; ++frg)
#pragma unroll
            for (int reg = 0; reg < 4; ++reg) {
                float ov = __shfl_xor(minv[frg][reg], mask, 64);
                int   oi = __shfl_xor(mini[frg][reg], mask, 64);
                if (ov < minv[frg][reg] ||
                    (ov == minv[frg][reg] && oi < mini[frg][reg])) {
                    minv[frg][reg] = ov; mini[frg][reg] = oi;
                }
            }
    }
    // rows are wave-private: direct write, no cross-wave reduction needed
    if (row16 == 0) {
#pragma unroll
        for (int frg = 0; frg < 2; ++frg)
#pragma unroll
            for (int reg = 0; reg < 4; ++reg)
                indices[r0 + w * 32 + frg * 16 + quad * 4 + reg] = mini[frg][reg];
    }
}

// ---------------------------------------------------------------------------
// Single block: histogram (LDS atomics over 256 KB of indices), EMA cluster
// stats, perplexity, prefix-sum -> cursor, smoothed.
__global__ __launch_bounds__(1024) void finalize_kernel(const int* __restrict__ indices,
                                                        const float* __restrict__ ema_c,
                                                        const int* __restrict__ counter,
                                                        float* __restrict__ out_perp,
                                                        int* __restrict__ cursor,
                                                        float* __restrict__ smoothed) {
    const int k = threadIdx.x;
    __shared__ int hist[1024];
    __shared__ float fred[1024];
    __shared__ int scan[1024];
    __shared__ float nsum_s;

    hist[k] = 0;
    __syncthreads();
    // 65536 indices = 16384 int4; 16 per thread, fully coalesced
    const int4* idx4 = (const int4*)indices;
#pragma unroll 4
    for (int i = 0; i < 16; ++i) {
        int4 v = idx4[(size_t)i * 1024 + k];
        atomicAdd(&hist[v.x], 1);
        atomicAdd(&hist[v.y], 1);
        atomicAdd(&hist[v.z], 1);
        atomicAdd(&hist[v.w], 1);
    }
    __syncthreads();

    const int c = hist[k];
    const float bias = 1.0f - powf(GAMMA, (float)counter[0]);
    const float hid = fmaf(ema_c[k], GAMMA, (float)c * (1.0f - GAMMA));
    const float avg = hid / bias;

    fred[k] = avg;
    __syncthreads();
    for (int s = 512; s >= 1; s >>= 1) {
        if (k < s) fred[k] += fred[k + s];
        __syncthreads();
    }
    if (k == 0) nsum_s = fred[0];
    __syncthreads();
    const float nsum = nsum_s;

    float p = (float)c * (1.0f / (float)N);
    fred[k] = p * logf(p + 1e-10f);
    __syncthreads();
    for (int s = 512; s >= 1; s >>= 1) {
        if (k < s) fred[k] += fred[k + s];
        __syncthreads();
    }
    if (k == 0) out_perp[0] = expf(-fred[0]);

    scan[k] = c;
    __syncthreads();
    for (int s = 1; s < 1024; s <<= 1) {
        int v = (k >= s) ? scan[k - s] : 0;
        __syncthreads();
        scan[k] += v;
        __syncthreads();
    }
    cursor[k] = scan[k] - c;

    smoothed[k] = (avg + EPS) / (nsum + (float)K * EPS) * nsum;
}

// ---------------------------------------------------------------------------
// Build packed permutation (n | k<<16), grouped by cluster; also zero dwT
// (65536 threads x float4 = exactly K*D floats).
__global__ __launch_bounds__(256) void scatter_kernel(const int* __restrict__ indices,
                                                      int* __restrict__ cursor,
                                                      int* __restrict__ permk,
                                                      float* __restrict__ dwT) {
    const int n = blockIdx.x * 256 + threadIdx.x;
    *(float4*)&dwT[(size_t)n * 4] = make_float4(0.f, 0.f, 0.f, 0.f);
    const int k = indices[n];
    const int pos = atomicAdd(&cursor[k], 1);
    permk[pos] = n | (k << 16);
}

// ---------------------------------------------------------------------------
// Fused tail pass over cluster-sorted rows (the ONLY full x read besides
// argmin): segmented dw reduction + ste write (exact fp32 codebook rows)
// + loss partials. Uniform 64-row chunks -> perfectly balanced.
__global__ __launch_bounds__(256) void dw_fused_kernel(const float* __restrict__ x,
                                                       const float* __restrict__ cbT,
                                                       const int* __restrict__ permk,
                                                       float* __restrict__ ste,
                                                       float* __restrict__ dwT,
                                                       float* __restrict__ lossp) {
    __shared__ int s_rows[DWROWS];
    __shared__ int s_keys[DWROWS + 1];
    const int d = threadIdx.x;
    const int base = blockIdx.x * DWROWS;
    if (threadIdx.x < DWROWS) {
        const int pk = permk[base + threadIdx.x];
        s_rows[threadIdx.x] = pk & 0xffff;
        s_keys[threadIdx.x] = pk >> 16;
    }
    if (threadIdx.x == 0) s_keys[DWROWS] = -1;   // sentinel: force final flush
    __syncthreads();
    float acc = 0.f;
    float ls = 0.f;
#pragma unroll 4
    for (int i = 0; i < DWROWS; ++i) {
        const int n = s_rows[i];
        const int k = s_keys[i];
        const float xv = x[(size_t)n * D + d];
        const float q  = cbT[(size_t)k * D + d];   // L2-resident (4 MB working set)
        ste[(size_t)n * D + d] = q;
        acc += xv;
        const float df = q - xv;
        ls = fmaf(df, df, ls);
        if (s_keys[i + 1] != k) {                  // uniform branch (LDS keys)
            atomicAdd(&dwT[(size_t)k * D + d], acc);
            acc = 0.f;
        }
    }
    // loss partial: wave shuffle + cross-wave LDS reduce
#pragma unroll
    for (int off = 32; off >= 1; off >>= 1) ls += __shfl_down(ls, off, 64);
    __shared__ float red[4];
    if ((d & 63) == 0) red[d >> 6] = ls;
    __syncthreads();
    if (d == 0) lossp[blockIdx.x] = red[0] + red[1] + red[2] + red[3];
}

// ---------------------------------------------------------------------------
// out_cb[d][k] = ((ema_dw[d][k]*g + dwT[k][d]*(1-g))/bias)/smoothed[k]
// LDS 64x64 transpose so both global reads and writes are coalesced.
// Block 0 additionally reduces the 1024 loss partials -> out_loss.
__global__ __launch_bounds__(256) void codebook_final_kernel(const float* __restrict__ dwT,
                                                             const float* __restrict__ ema_dw,
                                                             const float* __restrict__ smoothed,
                                                             const int* __restrict__ counter,
                                                             const float* __restrict__ lossp,
                                                             float* __restrict__ out_cb,
                                                             float* __restrict__ out_loss) {
    __shared__ float tile[64][65];
    __shared__ float lred[4];
    const int tid = threadIdx.x;

    if (blockIdx.x == 0) {
        float s = lossp[tid] + lossp[tid + 256] + lossp[tid + 512] + lossp[tid + 768];
#pragma unroll
        for (int off = 32; off >= 1; off >>= 1) s += __shfl_down(s, off, 64);
        if ((tid & 63) == 0) lred[tid >> 6] = s;
        __syncthreads();
        if (tid == 0)
            out_loss[0] = BETA * (lred[0] + lred[1] + lred[2] + lred[3])
                          * (1.0f / ((float)N * (float)D));
        __syncthreads();
    }

    const int d0 = (blockIdx.x & 3) * 64;
    const int k0 = (blockIdx.x >> 2) * 64;
#pragma unroll
    for (int it = 0; it < 16; ++it) {
        int idx = it * 256 + tid;
        int kk = idx >> 6, dd = idx & 63;
        tile[kk][dd] = dwT[(size_t)(k0 + kk) * D + d0 + dd];   // coalesced in d
    }
    __syncthreads();
    const float bias = 1.0f - powf(GAMMA, (float)counter[0]);
#pragma unroll
    for (int it = 0; it < 16; ++it) {
        int idx = it * 256 + tid;
        int dd = idx >> 6, kk = idx & 63;
        float dwv = tile[kk][dd];                               // 2-way LDS alias: free
        float hid = fmaf(ema_dw[(size_t)(d0 + dd) * K + k0 + kk], GAMMA,
                         dwv * (1.0f - GAMMA));
        out_cb[(size_t)(d0 + dd) * K + k0 + kk] = (hid / bias) / smoothed[k0 + kk];
    }
}

// ---------------------------------------------------------------------------
extern "C" void kernel_launch(void* const* d_in, const int* in_sizes, int n_in,
                              void* d_out, int out_size, void* d_ws, size_t ws_size,
                              hipStream_t stream) {
    const float* x       = (const float*)d_in[0];  // [N, D]
    const float* cb      = (const float*)d_in[1];  // [D, K]
    const float* ema_c   = (const float*)d_in[2];  // [K]
    const float* ema_dw  = (const float*)d_in[3];  // [D, K]
    const int*   counter = (const int*)d_in[4];

    float* out = (float*)d_out;
    float* ste = out;                        // N*D
    float* out_perp = out + (size_t)N * D;   // 1
    float* out_loss = out_perp + 1;          // 1
    float* out_cb = out_perp + 2;            // D*K

    char* ws = (char*)d_ws;
    int* indices  = (int*)(ws + OFF_INDICES);
    int* permk    = (int*)(ws + OFF_PERM);
    float* cnorm  = (float*)(ws + OFF_CNORM);
    int* cursor   = (int*)(ws + OFF_CURSOR);
    float* smooth = (float*)(ws + OFF_SMOOTH);
    float* cbT    = (float*)(ws + OFF_CBT);
    s16x8* cbEp   = (s16x8*)(ws + OFF_CBE);
    float* dwT    = (float*)(ws + OFF_CBE);   // reuse: cbEp dead after argmin
    float* lossp  = (float*)(ws + OFF_CNORM); // reuse: cnorm dead after argmin

    // zero cnorm (4 KB)
    hipMemsetAsync(cnorm, 0, K * sizeof(float), stream);

    pack_cb<<<64, 256, 0, stream>>>(cb, cbT, cbEp, cnorm);
    argmin_mfma_kernel<<<N / 128, 256, 0, stream>>>(x, cbEp, cnorm, indices);
    finalize_kernel<<<1, 1024, 0, stream>>>(indices, ema_c, counter,
                                            out_perp, cursor, smooth);
    scatter_kernel<<<N / 256, 256, 0, stream>>>(indices, cursor, permk, dwT);
    dw_fused_kernel<<<N / DWROWS, 256, 0, stream>>>(x, cbT, permk, ste, dwT, lossp);
    codebook_final_kernel<<<64, 256, 0, stream>>>(dwT, ema_dw, smooth, counter,
                                                  lossp, out_cb, out_loss);
}